// Round 6
// baseline (727.326 us; speedup 1.0000x reference)
//
#include <hip/hip_runtime.h>
#include <cstdint>
#include <cstddef>

#define DEVI __device__ __forceinline__

typedef __bf16 bf16x8 __attribute__((ext_vector_type(8)));
typedef float  floatx4 __attribute__((ext_vector_type(4)));

constexpr int NHEAD = 6;
constexpr int CLF = 64, CHF = 192;
constexpr int IMG = 256;
constexpr int HW  = IMG * IMG;

// LDS pitches (bf16 elements). Row byte-stride multiple of 16 (ds_read_b128).
constexpr int P_WQ  = 72;   // staged WqT-all rows (64+8)
constexpr int P_WKV = 200;  // staged WkT/WvT slice rows (192+8)
constexpr int P_WO  = 40;   // staged WoT slice rows (32+8)
constexpr int P_HFH = 104;  // hf_n half staging rows (96+8); also epilogue O halves
constexpr int PQK = 40;     // K tile (64 x 32+8)
constexpr int PVT = 72;     // V^T (32 x 64+8)
constexpr int PP  = 72;     // lf staging / P / AO (64 x 64+8)

// LDS map (bytes), 512-thread block = 2 windows (win = tid>>8).
// Shared:  WKV slice [64][200] @0 (also WqT-all [192][72] = 27648 spanning into WO;
//          also per-window hf-half staging / epilogue halves at win*13312, 13312 B each)
//          WO slice [192][40] @25600;  RPB bf16 @78848 (2700)
// Per-win: K @40960+win*5120;  VT @51200+win*4608;  P @60416+win*9216
//          (LN stats 4KB alias the K region during load phase)
constexpr int OFF_WKV = 0;      // 25600
constexpr int OFF_WO  = 25600;  // 15360 -> 40960
constexpr int OFF_K0  = 40960;  // 2 x 5120 -> 51200
constexpr int OFF_VT0 = 51200;  // 2 x 4608 -> 60416
constexpr int OFF_P0  = 60416;  // 2 x 9216 -> 78848
constexpr int OFF_RPB = 78848;  // 2700 -> 81548
constexpr int SMEM_BYTES = 81552;  // rounds to 81920 (512B gran) -> exactly 2 blocks/CU

DEVI unsigned short f2b(float f) {  // fp32 -> bf16 RNE
  unsigned u = __float_as_uint(f);
  u += 0x7fffu + ((u >> 16) & 1u);
  return (unsigned short)(u >> 16);
}
DEVI float b2f(unsigned short s) { return __uint_as_float(((unsigned)s) << 16); }

DEVI floatx4 mfma_bf16(bf16x8 a, bf16x8 b, floatx4 c) {
  return __builtin_amdgcn_mfma_f32_16x16x32_bf16(a, b, c, 0, 0, 0);
}

// ---- prep: W[k][n] fp32 -> W^T[n][k] bf16 into workspace ----
__global__ void wca_prep(const float* __restrict__ Wq, const float* __restrict__ Wk,
                         const float* __restrict__ Wv, const float* __restrict__ Wo,
                         unsigned short* __restrict__ wT) {
  int i = blockIdx.x * 256 + threadIdx.x;  // grid covers exactly 122880
  if (i < 12288) {                         // WqT: 192 x 64
    int n = i >> 6, k = i & 63;
    wT[i] = f2b(Wq[k * 192 + n]);
  } else if (i < 49152) {                  // WkT: 192 x 192
    int j = i - 12288, n = j / 192, k = j - n * 192;
    wT[i] = f2b(Wk[k * 192 + n]);
  } else if (i < 86016) {                  // WvT
    int j = i - 49152, n = j / 192, k = j - n * 192;
    wT[i] = f2b(Wv[k * 192 + n]);
  } else {                                 // WoT
    int j = i - 86016, n = j / 192, k = j - n * 192;
    wT[i] = f2b(Wo[k * 192 + n]);
  }
}

__global__ __launch_bounds__(512, 4) void wca_main(
    const float* __restrict__ ylf, const float* __restrict__ yhf,
    const float* __restrict__ glf, const float* __restrict__ blf,
    const float* __restrict__ ghf, const float* __restrict__ bhf,
    const float* __restrict__ bq,  const float* __restrict__ bk,
    const float* __restrict__ bv,  const float* __restrict__ bo,
    const float* __restrict__ rpb, const unsigned short* __restrict__ wT,
    float* __restrict__ out) {
  __shared__ __align__(16) char smem[SMEM_BYTES];

  const int tid  = threadIdx.x;
  const int win  = tid >> 8;     // window within block (0/1)
  const int t256 = tid & 255;
  const int lane = tid & 63;
  const int wvw  = (tid >> 6) & 3;   // wave within window 0..3
  const int quad = lane >> 4;
  const int l16  = lane & 15;

  unsigned short* s_wkv = (unsigned short*)(smem + OFF_WKV);
  unsigned short* s_wq  = s_wkv;  // [192][72], spans into WO region
  unsigned short* s_wo  = (unsigned short*)(smem + OFF_WO);
  unsigned short* s_hfh = (unsigned short*)(smem + win * 13312);  // [64][104]
  unsigned short* s_k   = (unsigned short*)(smem + OFF_K0  + win * 5120);
  unsigned short* s_vt  = (unsigned short*)(smem + OFF_VT0 + win * 4608);
  unsigned short* s_lf  = (unsigned short*)(smem + OFF_P0  + win * 9216);
  unsigned short* s_p   = s_lf;
  float* s_red = (float*)(smem + OFF_K0 + win * 5120);  // stats die before first K write
  unsigned short* s_rpb = (unsigned short*)(smem + OFF_RPB);

  // XCD swizzle on PAIRS: XCD x owns contiguous pairs [x*256,+256). Each block's
  // two windows are wx-adjacent -> the two 32B halves of every 64B input line
  // are consumed inside one block (single fetch).
  const int g      = blockIdx.x;               // 2048 blocks
  const int pairid = ((g & 7) << 8) | (g >> 3);  // bijective on [0,2048)
  const int wid    = pairid * 2 + win;
  const int b   = wid >> 10;
  const int wy  = (wid >> 5) & 31;
  const int wx  = wid & 31;
  const int h0  = wy << 3, w0 = wx << 3;

  const int t_own = tid & 63;          // token owned for load/stats
  const int cg    = (tid >> 6) & 3;    // channel block owner (wave-uniform)
  const int ty    = t_own >> 3, tx = t_own & 7;

  // ---- load windows (coalesced 32B row segments) + LN stats in fp32 ----
  float lfv[16], hfv[48];
  float ls = 0.f, l2 = 0.f, hs = 0.f, h2 = 0.f;
  {
    const float* p = ylf + ((size_t)(b * CLF + cg * 16) * IMG + (h0 + ty)) * IMG + (w0 + tx);
#pragma unroll
    for (int k = 0; k < 16; k++) {
      float v = p[(size_t)k * HW];
      lfv[k] = v; ls += v; l2 += v * v;
    }
  }
  {
    const float* p = yhf + ((size_t)(b * CHF + cg * 48) * IMG + (h0 + ty)) * IMG + (w0 + tx);
#pragma unroll
    for (int k = 0; k < 48; k++) {
      float v = p[(size_t)k * HW];
      hfv[k] = v; hs += v; h2 += v * v;
    }
  }
  s_red[0 * 256 + (cg << 6) + t_own] = ls;
  s_red[1 * 256 + (cg << 6) + t_own] = l2;
  s_red[2 * 256 + (cg << 6) + t_own] = hs;
  s_red[3 * 256 + (cg << 6) + t_own] = h2;
  __syncthreads();  // B1
  float su = 0.f, sq = 0.f, hu = 0.f, hq = 0.f;
#pragma unroll
  for (int gg = 0; gg < 4; gg++) {
    su += s_red[0 * 256 + (gg << 6) + t_own];
    sq += s_red[1 * 256 + (gg << 6) + t_own];
    hu += s_red[2 * 256 + (gg << 6) + t_own];
    hq += s_red[3 * 256 + (gg << 6) + t_own];
  }
  const float mu_lf = su * (1.f / 64.f);
  const float rs_lf = rsqrtf(sq * (1.f / 64.f) - mu_lf * mu_lf + 1e-5f);
  const float mu_hf = hu * (1.f / 192.f);
  const float rs_hf = rsqrtf(hq * (1.f / 192.f) - mu_hf * mu_hf + 1e-5f);

  // ---- lf staging (all threads) + hf HALF 0 (channels 0..95: cg 0,1) ----
#pragma unroll
  for (int j = 0; j < 4; j++) {
    uint64_t w = 0;
#pragma unroll
    for (int m = 0; m < 4; m++) {
      int c = cg * 16 + j * 4 + m;
      float v = (lfv[j * 4 + m] - mu_lf) * rs_lf * glf[c] + blf[c];
      w |= (uint64_t)f2b(v) << (16 * m);
    }
    *(uint64_t*)(s_lf + t_own * PP + cg * 16 + j * 4) = w;
  }
  if (cg < 2) {
#pragma unroll
    for (int j = 0; j < 12; j++) {
      uint64_t w = 0;
#pragma unroll
      for (int m = 0; m < 4; m++) {
        int c = cg * 48 + j * 4 + m;                 // in [0,96)
        float v = (hfv[j * 4 + m] - mu_hf) * rs_hf * ghf[c] + bhf[c];
        w |= (uint64_t)f2b(v) << (16 * m);
      }
      *(uint64_t*)(s_hfh + t_own * P_HFH + cg * 48 + j * 4) = w;
    }
  }
  __syncthreads();  // B2: lf + hf-half0 staged

  bf16x8 lfr0 = *(const bf16x8*)(s_lf + (wvw * 16 + l16) * PP + quad * 8);
  bf16x8 lfr1 = *(const bf16x8*)(s_lf + (wvw * 16 + l16) * PP + 32 + quad * 8);
  bf16x8 hfr[6];
#pragma unroll
  for (int ks = 0; ks < 3; ks++)
    hfr[ks] = *(const bf16x8*)(s_hfh + (wvw * 16 + l16) * P_HFH + ks * 32 + quad * 8);
  __syncthreads();  // B2h: half0 reads done before half1 overwrites

  if (cg >= 2) {
#pragma unroll
    for (int j = 0; j < 12; j++) {
      uint64_t w = 0;
#pragma unroll
      for (int m = 0; m < 4; m++) {
        int c = cg * 48 + j * 4 + m;                 // in [96,192)
        float v = (hfv[j * 4 + m] - mu_hf) * rs_hf * ghf[c] + bhf[c];
        w |= (uint64_t)f2b(v) << (16 * m);
      }
      *(uint64_t*)(s_hfh + t_own * P_HFH + (cg - 2) * 48 + j * 4) = w;
    }
  }
  __syncthreads();  // B3: half1 staged
#pragma unroll
  for (int ks = 0; ks < 3; ks++)
    hfr[3 + ks] = *(const bf16x8*)(s_hfh + (wvw * 16 + l16) * P_HFH + ks * 32 + quad * 8);
  __syncthreads();  // B3b: all hf reads done; WKV/WO arena reusable

  const unsigned short* wqT = wT;           // [192][64]
  const unsigned short* wkT = wT + 12288;   // [192][192]
  const unsigned short* wvT = wT + 49152;
  const unsigned short* woT = wT + 86016;

  // ---- stage WqT-all (shared, contiguous 16B pieces) + rpb ----
#pragma unroll
  for (int i = 0; i < 3; i++) {
    int p = i * 512 + tid;            // 1536 pieces (192 rows x 8)
    int n = p >> 3, sub = p & 7;
    *(uint4*)(s_wq + n * P_WQ + sub * 8) = *(const uint4*)(wqT + n * 64 + sub * 8);
  }
  for (int i = tid; i < 225 * NHEAD; i += 512) s_rpb[i] = f2b(rpb[i]);
  __syncthreads();  // B4

  const int rowbase = wvw * 16 + quad * 4;   // C-layout row base for this lane

  // ---- Q for ALL heads upfront; fragments kept in registers (24 VGPR) ----
  bf16x8 aq[NHEAD];
#pragma unroll
  for (int h = 0; h < NHEAD; h++) {
#pragma unroll
    for (int nt = 0; nt < 2; nt++) {
      const int n = h * 32 + nt * 16 + l16;
      floatx4 acc = {0.f, 0.f, 0.f, 0.f};
      acc = mfma_bf16(lfr0, *(const bf16x8*)(s_wq + n * P_WQ + quad * 8), acc);
      acc = mfma_bf16(lfr1, *(const bf16x8*)(s_wq + n * P_WQ + 32 + quad * 8), acc);
      const float bqv = bq[n];
#pragma unroll
      for (int r = 0; r < 4; r++)
        s_p[(rowbase + r) * PP + nt * 16 + l16] = f2b(acc[r] + bqv);
    }
    aq[h] = *(const bf16x8*)(s_p + (wvw * 16 + l16) * PP + quad * 8);  // wave-local
  }
  __syncthreads();  // B5: s_wq reads done everywhere

  // shared staging of the per-head WkT/WvT slices (contiguous in wT)
  auto stageKV = [&](int h) {
    const unsigned short* sk = wkT + h * 6144;   // 32 rows x 192
    const unsigned short* sv = wvT + h * 6144;
#pragma unroll
    for (int i = 0; i < 3; i++) {
      int p = i * 512 + tid;          // 1536 pieces: K 0..767, V 768..1535
      if (p < 768) {
        int nl = p / 24, sub = p - nl * 24;
        *(uint4*)(s_wkv + nl * P_WKV + sub * 8) = *(const uint4*)(sk + nl * 192 + sub * 8);
      } else {
        int q = p - 768;
        int nl = q / 24, sub = q - nl * 24;
        *(uint4*)(s_wkv + (32 + nl) * P_WKV + sub * 8) = *(const uint4*)(sv + nl * 192 + sub * 8);
      }
    }
  };

  stageKV(0);
  __syncthreads();  // S0: KV(0) staged

  floatx4 oa[12];
  const floatx4 zero = {0.f, 0.f, 0.f, 0.f};
#pragma unroll
  for (int ct = 0; ct < 12; ct++) oa[ct] = zero;

#pragma unroll
  for (int h = 0; h < NHEAD; h++) {
    // ---- K_h -> s_k (A from hfr regs, B from staged LDS) ----
#pragma unroll
    for (int nt = 0; nt < 2; nt++) {
      const int n = h * 32 + nt * 16 + l16;
      const int nl = nt * 16 + l16;
      floatx4 acc = {0.f, 0.f, 0.f, 0.f};
#pragma unroll
      for (int ks = 0; ks < 6; ks++)
        acc = mfma_bf16(hfr[ks], *(const bf16x8*)(s_wkv + nl * P_WKV + ks * 32 + quad * 8), acc);
      const float bkv = bk[n];
#pragma unroll
      for (int r = 0; r < 4; r++)
        s_k[(rowbase + r) * PQK + nt * 16 + l16] = f2b(acc[r] + bkv);
    }
    // ---- V_h -> s_vt (transposed store) ----
#pragma unroll
    for (int nt = 0; nt < 2; nt++) {
      const int n = h * 32 + nt * 16 + l16;
      const int nl = nt * 16 + l16;
      floatx4 acc = {0.f, 0.f, 0.f, 0.f};
#pragma unroll
      for (int ks = 0; ks < 6; ks++)
        acc = mfma_bf16(hfr[ks], *(const bf16x8*)(s_wkv + (32 + nl) * P_WKV + ks * 32 + quad * 8), acc);
      const float bvv = bv[n];
#pragma unroll
      for (int r = 0; r < 4; r++)
        s_vt[(nt * 16 + l16) * PVT + rowbase + r] = f2b(acc[r] + bvv);
    }
    __syncthreads();  // A(h): s_k/s_vt visible; WKV slice dead for all waves

    // ---- stage WoT(h) + prefetch KV(h+1); retires under the attn math ----
#pragma unroll
    for (int i = 0; i < 2; i++) {
      int p = i * 512 + tid;          // 768 pieces: 192 rows x 4
      if (p < 768) {
        int n = p >> 2, sub = p & 3;
        *(uint4*)(s_wo + n * P_WO + sub * 8) = *(const uint4*)(woT + n * 192 + h * 32 + sub * 8);
      }
    }
    if (h + 1 < NHEAD) stageKV(h + 1);

    // ---- S = Q K^T * scale + rpb (wave owns query rows wvw*16..+15) ----
    float sv[4][4];
#pragma unroll
    for (int ct = 0; ct < 4; ct++) {
      bf16x8 kb = *(const bf16x8*)(s_k + (ct * 16 + l16) * PQK + quad * 8);
      floatx4 acc = {0.f, 0.f, 0.f, 0.f};
      acc = mfma_bf16(aq[h], kb, acc);
#pragma unroll
      for (int r = 0; r < 4; r++) {
        int row = rowbase + r, col = ct * 16 + l16;
        int dy = (row >> 3) - (col >> 3) + 7;
        int dx = (row & 7) - (col & 7) + 7;
        sv[ct][r] = acc[r] * 0.17677669529663688f + b2f(s_rpb[(dy * 15 + dx) * NHEAD + h]);
      }
    }
    // ---- softmax over 64 keys ----
#pragma unroll
    for (int r = 0; r < 4; r++) {
      float m = fmaxf(fmaxf(sv[0][r], sv[1][r]), fmaxf(sv[2][r], sv[3][r]));
      m = fmaxf(m, __shfl_xor(m, 1));
      m = fmaxf(m, __shfl_xor(m, 2));
      m = fmaxf(m, __shfl_xor(m, 4));
      m = fmaxf(m, __shfl_xor(m, 8));
      const float L2E = 1.4426950408889634f;
      float e0 = exp2f((sv[0][r] - m) * L2E);
      float e1 = exp2f((sv[1][r] - m) * L2E);
      float e2 = exp2f((sv[2][r] - m) * L2E);
      float e3 = exp2f((sv[3][r] - m) * L2E);
      float s = e0 + e1 + e2 + e3;
      s += __shfl_xor(s, 1);
      s += __shfl_xor(s, 2);
      s += __shfl_xor(s, 4);
      s += __shfl_xor(s, 8);
      float inv = 1.f / s;
      sv[0][r] = e0 * inv; sv[1][r] = e1 * inv; sv[2][r] = e2 * inv; sv[3][r] = e3 * inv;
    }
#pragma unroll
    for (int ct = 0; ct < 4; ct++)
#pragma unroll
      for (int r = 0; r < 4; r++)
        s_p[(rowbase + r) * PP + ct * 16 + l16] = f2b(sv[ct][r]);

    // ---- PV (wave-local P round trip; in-order DS) ----
    floatx4 pv0 = {0.f, 0.f, 0.f, 0.f}, pv1 = {0.f, 0.f, 0.f, 0.f};
#pragma unroll
    for (int ks = 0; ks < 2; ks++) {
      bf16x8 pa = *(const bf16x8*)(s_p + (wvw * 16 + l16) * PP + ks * 32 + quad * 8);
      pv0 = mfma_bf16(pa, *(const bf16x8*)(s_vt + (0 * 16 + l16) * PVT + ks * 32 + quad * 8), pv0);
      pv1 = mfma_bf16(pa, *(const bf16x8*)(s_vt + (1 * 16 + l16) * PVT + ks * 32 + quad * 8), pv1);
    }
#pragma unroll
    for (int r = 0; r < 4; r++) {
      s_p[(rowbase + r) * PP + l16]      = f2b(pv0[r]);
      s_p[(rowbase + r) * PP + 16 + l16] = f2b(pv1[r]);
    }
    bf16x8 aoh = *(const bf16x8*)(s_p + (wvw * 16 + l16) * PP + quad * 8);
    __syncthreads();  // A2(h): WoT(h)+KV(h+1) published; s_k/s_vt reads done

    // ---- O += AO_h @ Wo[h*32:+32, :] ----
#pragma unroll
    for (int ct = 0; ct < 12; ct++) {
      bf16x8 bb = *(const bf16x8*)(s_wo + (ct * 16 + l16) * P_WO + quad * 8);
      oa[ct] = mfma_bf16(aoh, bb, oa[ct]);
    }
  }
  __syncthreads();  // Bend: all s_wo/s_wkv reads done before epilogue overwrites

  // ---- epilogue: two 96-channel passes through the per-window half region ----
#pragma unroll
  for (int pass = 0; pass < 2; pass++) {
#pragma unroll
    for (int ct6 = 0; ct6 < 6; ct6++) {
      const int ct  = pass * 6 + ct6;
      const int col = ct * 16 + l16;           // global channel
      const float bov = bo[col];
#pragma unroll
      for (int r = 0; r < 4; r++)
        s_hfh[(rowbase + r) * P_HFH + (col - pass * 96)] = f2b(oa[ct][r] + bov);
    }
    __syncthreads();
#pragma unroll
    for (int k = 0; k < 6; k++) {
      int chunk = k * 256 + t256;              // 1536 chunks = 96ch x 64tok / 4
      int cl  = chunk >> 4;                    // [0,96)
      int sub = chunk & 15;
      int yy  = sub >> 1;
      int x4  = (sub & 1) << 2;
      int t0  = (yy << 3) + x4;
      int c   = pass * 96 + cl;
      size_t gidx = ((size_t)(b * CHF + c) * IMG + (h0 + yy)) * IMG + w0 + x4;
      float4 res = *(const float4*)(yhf + gidx);
      float4 v;
      v.x = b2f(s_hfh[(t0 + 0) * P_HFH + cl]) + res.x;
      v.y = b2f(s_hfh[(t0 + 1) * P_HFH + cl]) + res.y;
      v.z = b2f(s_hfh[(t0 + 2) * P_HFH + cl]) + res.z;
      v.w = b2f(s_hfh[(t0 + 3) * P_HFH + cl]) + res.w;
      *(float4*)(out + gidx) = v;
    }
    __syncthreads();
  }
}

extern "C" void kernel_launch(void* const* d_in, const int* in_sizes, int n_in,
                              void* d_out, int out_size, void* d_ws, size_t ws_size,
                              hipStream_t stream) {
  const float* ylf = (const float*)d_in[0];
  const float* yhf = (const float*)d_in[1];
  const float* glf = (const float*)d_in[2];
  const float* blf = (const float*)d_in[3];
  const float* ghf = (const float*)d_in[4];
  const float* bhf = (const float*)d_in[5];
  const float* Wq  = (const float*)d_in[6];
  const float* bq  = (const float*)d_in[7];
  const float* Wk  = (const float*)d_in[8];
  const float* bk  = (const float*)d_in[9];
  const float* Wv  = (const float*)d_in[10];
  const float* bv  = (const float*)d_in[11];
  const float* Wo  = (const float*)d_in[12];
  const float* bo  = (const float*)d_in[13];
  const float* rpb = (const float*)d_in[14];
  unsigned short* wT = (unsigned short*)d_ws;  // 122880 bf16 = 245760 B

  wca_prep<<<480, 256, 0, stream>>>(Wq, Wk, Wv, Wo, wT);
  wca_main<<<2048, 512, 0, stream>>>(ylf, yhf, glf, blf, ghf, bhf,
                                     bq, bk, bv, bo, rpb, wT, (float*)d_out);
}